// Round 15
// baseline (2632.770 us; speedup 1.0000x reference)
//
#include <hip/hip_runtime.h>

typedef unsigned int u32;
typedef unsigned long long u64;
typedef float v2f __attribute__((ext_vector_type(2)));

#define BB 4
#define NP0 4096
#define KNB 90
#define CC0 72
#define MAXD 1152
#define NSTRIPE 16
#define FSPLIT 700   // FPS(1) split point: [1,FSPLIT) in knnstd(0), [FSPLIT,1024) in feat(0)

// ---------------- fused input conversion (+ zero all per-stage sums) ----------------
__global__ void k_init(const float* __restrict__ xyz, const float* __restrict__ x,
                       float* __restrict__ xs, float* __restrict__ ys, float* __restrict__ zs,
                       float* __restrict__ feat, float* __restrict__ sums){
  int i = blockIdx.x*blockDim.x + threadIdx.x;
  if (i < 16) sums[i] = 0.f;
  if (i < BB*NP0){
    xs[i] = xyz[3*i+0];
    ys[i] = xyz[3*i+1];
    zs[i] = xyz[3*i+2];
  }
  if (i < BB*NP0*36){
    int j = i % 36; int bn = i / 36;
    int n = bn % NP0, b = bn / NP0;
    int cin = j / 12, f = j % 12;
    float xv = x[(b*3+cin)*NP0 + n];
    float rcp = __powf(1000.0f, -(float)f / 12.0f);
    float a = (100.0f * xv) * rcp;
    float sn, cs; __sincosf(a, &sn, &cs);
    float2 v = make_float2(sn, cs);
    *(float2*)(feat + (size_t)bn*CC0 + cin*24 + 2*f) = v;
  }
}

// Wave64 argmax: DPP fmax chain -> readlane(63) for max; ballot+ffs -> winning
// lane (smallest lane = smallest global index, jnp.argmax tie rule).
__device__ __forceinline__ void wave_argmax(float bd, int bi, float &smax, int &wbi){
  float v = bd;
  #define DPP_MAX(ctrl) do{ int _t = __builtin_amdgcn_mov_dpp(__float_as_int(v), (ctrl), 0xf, 0xf, true); \
                            v = fmaxf(v, __int_as_float(_t)); }while(0)
  DPP_MAX(0x111); DPP_MAX(0x112); DPP_MAX(0x114); DPP_MAX(0x118);
  DPP_MAX(0x142); DPP_MAX(0x143);
  #undef DPP_MAX
  smax = __int_as_float(__builtin_amdgcn_readlane(__float_as_int(v), 63));
  u64 msk = __ballot(bd == smax);
  int winlane = (int)__ffsll((long long)msk) - 1;
  wbi = __builtin_amdgcn_readlane(bi, winlane);
}

// ---------------- FPS stage 0 (standalone, exact, batch 0) ----------------
template<int PPT>
__global__ __launch_bounds__(256)
void k_fps4(const float* __restrict__ xs, const float* __restrict__ ys, const float* __restrict__ zs,
            int N, int G, int* __restrict__ fi,
            float* __restrict__ nxs, float* __restrict__ nys, float* __restrict__ nzs){
  constexpr int PH = PPT/2;
  __shared__ float4 sp[4096];
  __shared__ int sfi[2048];
  __shared__ u64 cand[2][4];
  int tid = threadIdx.x;
  const int base = tid * PPT;
  int wv = tid >> 6;
  int lane = tid & 63;
  v2f px[PH], py[PH], pz[PH], dmn[PH];
  #pragma unroll
  for (int j=0;j<PH;j++){
    int n = base + 2*j;
    float2 ax = *(const float2*)(xs+n);
    float2 ay = *(const float2*)(ys+n);
    float2 az = *(const float2*)(zs+n);
    px[j] = (v2f){ax.x, ax.y};
    py[j] = (v2f){ay.x, ay.y};
    pz[j] = (v2f){az.x, az.y};
    sp[n]   = make_float4(ax.x, ay.x, az.x, 0.f);
    sp[n+1] = make_float4(ax.y, ay.y, az.y, 0.f);
    dmn[j] = (v2f){INFINITY, INFINITY};
  }
  if (tid==0){ sfi[0]=0; }
  float lx = xs[0], ly = ys[0], lz = zs[0];
  __syncthreads();
  for (int t=1; t<G; t++){
    float bd = -INFINITY; int bi = base;
    v2f lx2 = (v2f){lx,lx}, ly2 = (v2f){ly,ly}, lz2 = (v2f){lz,lz};
    {
      #pragma clang fp contract(off)
      #pragma unroll
      for (int j=0;j<PH;j++){
        v2f dx = px[j] - lx2;
        v2f dy = py[j] - ly2;
        v2f dz = pz[j] - lz2;
        v2f d2 = (dx*dx + dy*dy) + dz*dz;
        v2f dmo = dmn[j];
        float dm0 = fminf(dmo.x, d2.x);
        float dm1 = fminf(dmo.y, d2.y);
        dmn[j] = (v2f){dm0, dm1};
        bool g0 = dm0 > bd;
        bd = g0 ? dm0 : bd;
        bi = g0 ? (base + 2*j) : bi;
        bool g1 = dm1 > bd;
        bd = g1 ? dm1 : bd;
        bi = g1 ? (base + 2*j + 1) : bi;
      }
    }
    float smax; int wbi;
    wave_argmax(bd, bi, smax, wbi);
    int par = t & 1;
    if (lane == 0) cand[par][wv] = ((u64)__float_as_uint(smax) << 32) | (u32)(~(u32)wbi);
    __syncthreads();
    u64 k0 = cand[par][0], k1 = cand[par][1], k2 = cand[par][2], k3 = cand[par][3];
    u64 ka = k0 > k1 ? k0 : k1;
    u64 kb = k2 > k3 ? k2 : k3;
    u64 km = ka > kb ? ka : kb;
    int w = (int)(~(u32)km);
    if ((u32)w >= (u32)N) w = 0;
    float4 p = sp[w];
    lx = p.x; ly = p.y; lz = p.z;
    if (tid==0){ sfi[t] = w; }
  }
  __syncthreads();
  for (int i = tid; i < G; i += 256) fi[i] = sfi[i];
  for (int i = tid; i < BB*G; i += 256){
    int b = i / G, g = i % G;
    int idx = sfi[g];
    nxs[i] = xs[(size_t)b*N + idx];
    nys[i] = ys[(size_t)b*N + idx];
    nzs[i] = zs[(size_t)b*N + idx];
  }
}

// ---------------- chunked FPS over current-stage centers (global state) ----------------
// Runs iterations [t0,t1) of FPS over the NF batch-0 centers (cxs/cys/czs).
// State across chunks: dmnG[NF] + cenG[0] (last center). fi2[t] stored in-loop.
// Winner coords read from GLOBAL (L1-hot) — no LDS staging, so the host
// kernel's LDS/occupancy is unaffected. If t1==NF/2 (final), does the
// all-batch next-center gather. Tie rules identical to jnp.argmax.
template<int NF, int NT>
__device__ __forceinline__
void fps_chunk(const float* __restrict__ cxs, const float* __restrict__ cys, const float* __restrict__ czs,
               int t0, int t1,
               float* __restrict__ dmnG, float4* __restrict__ cenG,
               int* __restrict__ fi2,
               float* __restrict__ n2xs, float* __restrict__ n2ys, float* __restrict__ n2zs,
               u64 (&cand)[2][4]){
  constexpr int PPT = NF/NT;
  constexpr int PH = PPT/2;
  constexpr int G2 = NF/2;
  constexpr int NW = NT/64;
  int tid = threadIdx.x;
  const int base = tid * PPT;
  int wv = tid >> 6, lane = tid & 63;
  v2f px[PH], py[PH], pz[PH], dmn[PH];
  #pragma unroll
  for (int j=0;j<PH;j++){
    int n = base + 2*j;
    float2 ax = *(const float2*)(cxs+n);
    float2 ay = *(const float2*)(cys+n);
    float2 az = *(const float2*)(czs+n);
    px[j] = (v2f){ax.x, ax.y};
    py[j] = (v2f){ay.x, ay.y};
    pz[j] = (v2f){az.x, az.y};
  }
  float lx, ly, lz;
  if (t0 == 1){
    #pragma unroll
    for (int j=0;j<PH;j++) dmn[j] = (v2f){INFINITY, INFINITY};
    if (tid==0) fi2[0] = 0;
    lx = cxs[0]; ly = cys[0]; lz = czs[0];
  } else {
    #pragma unroll
    for (int j=0;j<PH;j++){
      float2 dv = *(const float2*)(dmnG + base + 2*j);
      dmn[j] = (v2f){dv.x, dv.y};
    }
    float4 c = *cenG;
    lx = c.x; ly = c.y; lz = c.z;
  }
  for (int t=t0; t<t1; t++){
    float bd = -INFINITY; int bi = base;
    v2f lx2 = (v2f){lx,lx}, ly2 = (v2f){ly,ly}, lz2 = (v2f){lz,lz};
    {
      #pragma clang fp contract(off)
      #pragma unroll
      for (int j=0;j<PH;j++){
        v2f dx = px[j] - lx2;
        v2f dy = py[j] - ly2;
        v2f dz = pz[j] - lz2;
        v2f d2 = (dx*dx + dy*dy) + dz*dz;
        v2f dmo = dmn[j];
        float dm0 = fminf(dmo.x, d2.x);
        float dm1 = fminf(dmo.y, d2.y);
        dmn[j] = (v2f){dm0, dm1};
        bool g0 = dm0 > bd;
        bd = g0 ? dm0 : bd;
        bi = g0 ? (base + 2*j) : bi;
        bool g1 = dm1 > bd;
        bd = g1 ? dm1 : bd;
        bi = g1 ? (base + 2*j + 1) : bi;
      }
    }
    float smax; int wbi;
    wave_argmax(bd, bi, smax, wbi);
    int par = t & 1;
    if (lane == 0) cand[par][wv] = ((u64)__float_as_uint(smax) << 32) | (u32)(~(u32)wbi);
    __syncthreads();
    u64 km;
    if constexpr (NW == 4){
      u64 k0 = cand[par][0], k1 = cand[par][1], k2 = cand[par][2], k3 = cand[par][3];
      u64 ka = k0 > k1 ? k0 : k1;
      u64 kb = k2 > k3 ? k2 : k3;
      km = ka > kb ? ka : kb;
    } else {
      u64 k0 = cand[par][0], k1 = cand[par][1];
      km = k0 > k1 ? k0 : k1;
    }
    int w = (int)(~(u32)km);
    if ((u32)w >= (u32)NF) w = 0;
    lx = cxs[w]; ly = cys[w]; lz = czs[w];
    if (tid==0) fi2[t] = w;
  }
  if (t1 < G2){
    #pragma unroll
    for (int j=0;j<PH;j++)
      *(float2*)(dmnG + base + 2*j) = make_float2(dmn[j].x, dmn[j].y);
    if (tid==0) *cenG = make_float4(lx, ly, lz, 0.f);
  } else {
    __syncthreads();  // drain fi2 stores (barrier waits vmcnt); same-CU L1 serves reads
    for (int i = tid; i < BB*G2; i += NT){
      int b2 = i / G2, g2 = i % G2;
      int idx = fi2[g2];
      if ((u32)idx >= (u32)NF) idx = 0;
      n2xs[i] = cxs[(size_t)b2*NF + idx];
      n2ys[i] = cys[(size_t)b2*NF + idx];
      n2zs[i] = czs[(size_t)b2*NF + idx];
    }
  }
}

// ---------------- fused kNN (exact radix select) + std partials + FPS chunk ----------------
__device__ float blockReduceSum(float v, float* sRed){
  for (int off=32; off; off>>=1) v += __shfl_down(v, off, 64);
  int wid = threadIdx.x >> 6, lane = threadIdx.x & 63;
  __syncthreads();
  if (lane==0) sRed[wid] = v;
  __syncthreads();
  float r = 0;
  if (threadIdx.x == 0){ for (int i=0;i<4;i++) r += sRed[i]; }
  return r;
}

// NF>0: block 0 runs fps_chunk<NF,256> over [t0,t1); other blocks shift bid by 1.
template<int C, int NF>
__global__ __launch_bounds__(256)
void k_knnstd(const float* __restrict__ x,
              const float* __restrict__ xs, const float* __restrict__ ys, const float* __restrict__ zs,
              const float* __restrict__ nxs, const float* __restrict__ nys, const float* __restrict__ nzs,
              const int* __restrict__ fi, int N, int G,
              int* __restrict__ ki, float* __restrict__ sums,
              int t0, int t1, float* __restrict__ dmnG, float4* __restrict__ cenG,
              int* __restrict__ fi2, float* __restrict__ n2xs,
              float* __restrict__ n2ys, float* __restrict__ n2zs){
  extern __shared__ u32 smk[];
  __shared__ u64 candF[2][4];
  int tid = threadIdx.x;
  if constexpr (NF > 0){
    if (blockIdx.x == 0){
      fps_chunk<NF,256>(nxs, nys, nzs, t0, t1, dmnG, cenG, fi2, n2xs, n2ys, n2zs, candF);
      return;
    }
  }
  u32* keys = smk;           // N
  u32* hist = smk + N;       // 256
  u32* eq   = hist + 256;    // 512
  u32* sc   = eq + 512;      // [0]=prefix [1]=base [2]=outcnt [3]=eqcnt
  u32* wtot = sc + 4;        // 4 wave totals
  __shared__ float sLcx[C];
  __shared__ int sKi[KNB];
  __shared__ int sFi;
  __shared__ float sRed[4];
  int bid = (NF > 0) ? ((int)blockIdx.x - 1) : (int)blockIdx.x;
  int wv = tid >> 6, lane = tid & 63;
  int g = bid % G, b = bid / G;
  if (tid==0){ int f0 = fi[g]; if ((u32)f0 >= (u32)N) f0 = 0; sFi = f0; }
  float cx = nxs[b*G+g], cy = nys[b*G+g], cz = nzs[b*G+g];
  float ss = __fadd_rn(__fadd_rn(__fmul_rn(cx,cx), __fmul_rn(cy,cy)), __fmul_rn(cz,cz));
  for (int n = tid; n < N; n += 256){
    float px = xs[b*N+n], py = ys[b*N+n], pz = zs[b*N+n];
    float nn  = __fadd_rn(__fadd_rn(__fmul_rn(px,px), __fmul_rn(py,py)), __fmul_rn(pz,pz));
    float dot = __fadd_rn(__fadd_rn(__fmul_rn(cx,px), __fmul_rn(cy,py)), __fmul_rn(cz,pz));
    float sq  = __fsub_rn(__fadd_rn(ss, nn), __fmul_rn(2.0f, dot));
    u32 u = __float_as_uint(sq);
    keys[n] = (u & 0x80000000u) ? ~u : (u | 0x80000000u);
  }
  if (tid < 4) sc[tid] = 0;
  __syncthreads();
  for (int c = tid; c < C; c += 256) sLcx[c] = x[(size_t)(b*N + sFi)*C + c];
  u32 prefix = 0, bas = 0;
  for (int pass=0; pass<4; pass++){
    int shift = 24 - 8*pass;
    u32 mask = (pass==0) ? 0u : (0xFFFFFFFFu << (shift+8));
    hist[tid] = 0;
    __syncthreads();
    for (int n = tid; n < N; n += 256){
      u32 k = keys[n];
      if ((k & mask) == (prefix & mask))
        atomicAdd(&hist[(k >> shift) & 255u], 1u);
    }
    __syncthreads();
    u32 h = hist[tid];
    u32 p = h;
    #pragma unroll
    for (int off=1; off<64; off<<=1){
      u32 o = __shfl_up(p, off, 64);
      if (lane >= off) p += o;
    }
    if (lane == 63) wtot[wv] = p;
    __syncthreads();
    u32 ex = p - h;
    for (int w2=0; w2<wv; w2++) ex += wtot[w2];
    if (bas + ex < KNB && bas + ex + h >= KNB){
      sc[0] = prefix | ((u32)tid << shift);
      sc[1] = bas + ex;
    }
    __syncthreads();
    prefix = sc[0]; bas = sc[1];
    __syncthreads();
  }
  u32 T = prefix;
  int needEq = KNB - (int)bas;
  int* out = ki + (size_t)(b*G+g)*KNB;
  for (int n = tid; n < N; n += 256){
    u32 k = keys[n];
    if (k < T){
      u32 p2 = atomicAdd(&sc[2], 1u);
      if (p2 < KNB){ out[p2] = n; sKi[p2] = n; }
    } else if (k == T){
      u32 e = atomicAdd(&sc[3], 1u);
      if (e < 512) eq[e] = (u32)n;
    }
  }
  __syncthreads();
  int m = (int)sc[3]; if (m > 512) m = 512;
  for (int i = tid; i < m; i += 256){
    u32 v = eq[i];
    int r = 0;
    for (int j=0; j<m; j++) r += (eq[j] < v);
    if (r < needEq){
      u32 p2 = atomicAdd(&sc[2], 1u);
      if (p2 < KNB){ out[p2] = (int)v; sKi[p2] = (int)v; }
    }
  }
  __syncthreads();
  if (tid == 0){
    u32 c = sc[2];
    while (c < KNB){ out[c] = 0; sKi[c] = 0; c++; }
  }
  __syncthreads();
  float s1=0, s2=0, s3=0, s4=0;
  constexpr int C2 = C/2;
  for (int u2 = tid; u2 < KNB*C2; u2 += 256){
    int k = u2 / C2; int c = (u2 - k*C2)*2;
    int idx = sKi[k];
    float2 v = *(const float2*)(x + (size_t)(b*N + idx)*C + c);
    float a0 = v.x - sLcx[c];
    float a1 = v.y - sLcx[c+1];
    s1 += a0 + a1; s2 += a0*a0 + a1*a1;
  }
  if (tid < 3){
    for (int k=0;k<KNB;k++){
      int idx = sKi[k];
      float pc = (tid==0 ? xs[b*N+idx] : tid==1 ? ys[b*N+idx] : zs[b*N+idx]);
      float cc = (tid==0 ? cx : tid==1 ? cy : cz);
      float w = pc - cc;
      s3 += w; s4 += w*w;
    }
  }
  float t;
  t = blockReduceSum(s1, sRed); if (tid==0) atomicAdd(&sums[0], t);
  t = blockReduceSum(s2, sRed); if (tid==0) atomicAdd(&sums[1], t);
  t = blockReduceSum(s3, sRed); if (tid==0) atomicAdd(&sums[2], t);
  t = blockReduceSum(s4, sRed); if (tid==0) atomicAdd(&sums[3], t);
}

// ---------------- main feature kernel (+ optional FPS chunk in block 0) ----------------
template<int C, int NF, int NT>
__global__ void k_feat(const float* __restrict__ x,
            const float* __restrict__ xs, const float* __restrict__ ys, const float* __restrict__ zs,
            const float* __restrict__ nxs, const float* __restrict__ nys, const float* __restrict__ nzs,
            const int* __restrict__ fi, const int* __restrict__ ki, const float* __restrict__ sums,
            double n1, double n2,
            int N, int G, float* __restrict__ lc,
            int t0, int t1, float* __restrict__ dmnG, float4* __restrict__ cenG,
            int* __restrict__ fi2, float* __restrict__ n2xs,
            float* __restrict__ n2ys, float* __restrict__ n2zs){
  constexpr int D = 2*C;
  constexpr int D3 = D/3;
  constexpr int FD = C/3;
  __shared__ u64 candF[2][4];
  __shared__ float sLcx[C];
  __shared__ float sDx[KNB*3];
  __shared__ int sKi[KNB];
  __shared__ int sFi;
  __shared__ float sC[3];
  __shared__ float sInv2[2];
  int tid = threadIdx.x;
  if constexpr (NF > 0){
    if (blockIdx.x == 0){
      fps_chunk<NF,NT>(nxs, nys, nzs, t0, t1, dmnG, cenG, fi2, n2xs, n2ys, n2zs, candF);
      return;
    }
  }
  int bid = (NF > 0) ? ((int)blockIdx.x - 1) : (int)blockIdx.x;
  int g = bid % G, b = bid / G;
  if (tid==0){ int f0 = fi[g]; if ((u32)f0 >= (u32)N) f0 = 0; sFi = f0; }
  if (tid==0){
    double s1 = sums[0], s2 = sums[1];
    double mean = s1/n1;
    double var = (s2 - s1*mean)/(n1 - 1.0); if (var < 0) var = 0;
    sInv2[0] = (float)(1.0/(sqrt(var) + 1e-5));
    double t1d = sums[2], t2d = sums[3];
    double m2 = t1d/n2;
    double v2 = (t2d - t1d*m2)/(n2 - 1.0); if (v2 < 0) v2 = 0;
    sInv2[1] = (float)(1.0/(sqrt(v2) + 1e-5));
  }
  if (tid<3) sC[tid] = (tid==0 ? nxs[b*G+g] : tid==1 ? nys[b*G+g] : nzs[b*G+g]);
  if (tid < KNB){ int v = ki[(size_t)(b*G+g)*KNB + tid]; if ((u32)v >= (u32)N) v = 0; sKi[tid] = v; }
  __syncthreads();
  for (int c = tid; c < C; c += blockDim.x) sLcx[c] = x[(size_t)(b*N + sFi)*C + c];
  for (int t = tid; t < KNB*3; t += blockDim.x){
    int k = t/3, c = t%3;
    int idx = sKi[k];
    float pc = (c==0 ? xs[b*N+idx] : c==1 ? ys[b*N+idx] : zs[b*N+idx]);
    sDx[t] = (pc - sC[c]) * sInv2[1];
  }
  __syncthreads();
  int p = tid;
  if (p >= C) return;
  int d0 = 2*p;
  int c = d0 / D3;
  int f = (d0 - c*D3) >> 1;
  float rcp = __powf(1000.0f, -(float)f / (float)FD);
  bool low = (d0 < C);
  float invdx = sInv2[0];
  float fh0 = 0.f, fh1 = 0.f;
  if (!low){ fh0 = sLcx[d0-C]; fh1 = sLcx[d0+1-C]; }
  float l0 = low ? sLcx[d0] : 0.f, l1 = low ? sLcx[d0+1] : 0.f;
  float mx0=-INFINITY, mx1=-INFINITY, sm0=0.f, sm1=0.f;
  for (int k=0;k<KNB;k++){
    float a = (100.0f * sDx[k*3+c]) * rcp;
    float sn, cs; __sincosf(a, &sn, &cs);
    float f0, f1;
    if (low){
      float2 v = *(const float2*)(x + (size_t)(b*N + sKi[k])*C + d0);
      f0 = (v.x - l0) * invdx;
      f1 = (v.y - l1) * invdx;
    } else { f0 = fh0; f1 = fh1; }
    float w0 = (f0 + sn)*sn;
    float w1 = (f1 + cs)*cs;
    mx0 = fmaxf(mx0, w0); sm0 += w0;
    mx1 = fmaxf(mx1, w1); sm1 += w1;
  }
  float* o = lc + (size_t)(b*G+g)*D + d0;
  o[0] = mx0 + sm0/90.0f;
  o[1] = mx1 + sm1/90.0f;
}

// ---------------- BatchNorm: parallel partial stats ----------------
__global__ __launch_bounds__(256)
void k_bnpart(const float* __restrict__ lc, int D, int M,
              double* __restrict__ PS, double* __restrict__ PQ){
  __shared__ double sS[4][64], sQ[4][64];
  int lane = threadIdx.x & 63, row = threadIdx.x >> 6;
  int tile = blockIdx.x, stripe = blockIdx.y;
  int d = tile*64 + lane;
  int span = M / NSTRIPE;
  int i0 = stripe * span;
  double s=0, q=0;
  if (d < D){
    for (int i=i0+row; i<i0+span; i+=4){
      float v = lc[(size_t)i*D + d];
      s += v; q += (double)v*v;
    }
  }
  sS[row][lane]=s; sQ[row][lane]=q;
  __syncthreads();
  if (row==0 && d < D){
    PS[(size_t)stripe*MAXD + d] = sS[0][lane]+sS[1][lane]+sS[2][lane]+sS[3][lane];
    PQ[(size_t)stripe*MAXD + d] = sQ[0][lane]+sQ[1][lane]+sQ[2][lane]+sQ[3][lane];
  }
}

__global__ void k_bnfin(const double* __restrict__ PS, const double* __restrict__ PQ,
                        const float* __restrict__ gamma, const float* __restrict__ beta,
                        int D, int M, float* __restrict__ A, float* __restrict__ Bb){
  int d = blockIdx.x*64 + threadIdx.x;
  if (d >= D) return;
  double ts=0, tq=0;
  for (int s=0; s<NSTRIPE; s++){ ts += PS[(size_t)s*MAXD + d]; tq += PQ[(size_t)s*MAXD + d]; }
  double mean = ts / M;
  double var = tq / M - mean*mean; if (var < 0) var = 0;
  float rstd = (float)(1.0/sqrt(var + 1e-5));
  float gm = gamma[d], bt = beta[d];
  A[d] = gm*rstd;
  Bb[d] = bt - (float)mean*gm*rstd;
}

// in-place BN + GELU — large coalesced grid
__global__ void k_apply(float* __restrict__ lc, const float* __restrict__ A,
                        const float* __restrict__ Bb, int D, int total){
  int i = blockIdx.x*blockDim.x + threadIdx.x;
  if (i >= total) return;
  int d = i % D;
  float v = lc[i]*A[d] + Bb[d];
  lc[i] = 0.5f * v * (1.0f + erff(v * 0.70710678118654752f));
}

__global__ void k_out(const float* __restrict__ feat, float* __restrict__ out){
  int i = blockIdx.x*blockDim.x + threadIdx.x;
  if (i >= BB*1152) return;
  int b = i / 1152, d = i % 1152;
  const float* base = feat + (size_t)b*256*1152 + d;
  float mx = -INFINITY, sm = 0.f;
  for (int g=0; g<256; g++){
    float v = base[(size_t)g*1152];
    mx = fmaxf(mx, v); sm += v;
  }
  out[i] = mx + sm/256.0f;
}

// ---------------- launch ----------------
extern "C" void kernel_launch(void* const* d_in, const int* in_sizes, int n_in,
                              void* d_out, int out_size, void* d_ws, size_t ws_size,
                              hipStream_t stream) {
  const float* xyz = (const float*)d_in[0];
  const float* xin = (const float*)d_in[1];
  float* ws = (float*)d_ws;
  size_t off = 0;
  const size_t PS_ = (size_t)BB*NP0;
  const size_t XS = (size_t)BB*NP0*CC0;
  float* T0[3]; float* T1[3]; float* T2[3];
  for (int i=0;i<3;i++){ T0[i] = ws + off; off += PS_; }
  for (int i=0;i<3;i++){ T1[i] = ws + off; off += PS_; }
  for (int i=0;i<3;i++){ T2[i] = ws + off; off += PS_; }
  float* xA = ws + off; off += XS;
  float* xB = ws + off; off += XS;
  int*   fiA = (int*)(ws + off); off += 2048;
  int*   fiB = (int*)(ws + off); off += 2048;
  int*   ki = (int*)(ws + off); off += (size_t)BB*2048*KNB;
  float* sums = ws + off; off += 16;
  float* Abn  = ws + off; off += 1152;
  float* Bbn  = ws + off; off += 1152;
  float* dmnG = ws + off; off += 2048;
  float4* cenG = (float4*)(ws + off); off += 4;
  off = (off + 1) & ~(size_t)1;
  double* PSb = (double*)(ws + off); off += (size_t)NSTRIPE*MAXD*2;
  double* PQb = (double*)(ws + off); off += (size_t)NSTRIPE*MAXD*2;

  k_init<<<(BB*NP0*36+255)/256, 256, 0, stream>>>(xyz, xin, T0[0], T0[1], T0[2], xA, sums);
  k_fps4<16><<<1, 256, 0, stream>>>(T0[0],T0[1],T0[2], NP0, NP0/2, fiA, T1[0],T1[1],T1[2]);

  float **P = T0, **Cn = T1, **Nx = T2;
  int *fiC = fiA, *fiN = fiB;
  float *xc = xA, *lc = xB;
  for (int s=0; s<4; s++){
    int N = NP0 >> s, G = N >> 1, C = CC0 << s, D = 2*C;
    float* ssum = sums + 4*s;
    size_t knn_lds = (size_t)(N + 256 + 512 + 8 + 8)*4;
    if (s==0){
      // FPS(1) chunk A: iters [1, FSPLIT)
      k_knnstd<72,2048><<<BB*G+1, 256, knn_lds, stream>>>(xc, P[0],P[1],P[2], Cn[0],Cn[1],Cn[2],
          fiC, N, G, ki, ssum, 1, FSPLIT, dmnG, cenG, fiN, Nx[0],Nx[1],Nx[2]);
    } else if (s==1){
      k_knnstd<144,1024><<<BB*G+1, 256, knn_lds, stream>>>(xc, P[0],P[1],P[2], Cn[0],Cn[1],Cn[2],
          fiC, N, G, ki, ssum, 1, 512, dmnG, cenG, fiN, Nx[0],Nx[1],Nx[2]);
    } else if (s==2){
      k_knnstd<288,512><<<BB*G+1, 256, knn_lds, stream>>>(xc, P[0],P[1],P[2], Cn[0],Cn[1],Cn[2],
          fiC, N, G, ki, ssum, 1, 256, dmnG, cenG, fiN, Nx[0],Nx[1],Nx[2]);
    } else {
      k_knnstd<576,0><<<BB*G, 256, knn_lds, stream>>>(xc, P[0],P[1],P[2], Cn[0],Cn[1],Cn[2],
          fiC, N, G, ki, ssum, 0, 0, nullptr, nullptr, nullptr, nullptr, nullptr, nullptr);
    }
    double n1 = (double)BB*G*KNB*C, n2 = (double)BB*G*KNB*3;
    int Tp = ((C + 63)/64)*64;
    if (s==0){
      // FPS(1) chunk B: iters [FSPLIT, 1024) + gather, block 0 of feat
      k_feat<72,2048,128><<<BB*G+1, Tp, 0, stream>>>(xc, P[0],P[1],P[2], Cn[0],Cn[1],Cn[2], fiC, ki, ssum,
          n1, n2, N, G, lc, FSPLIT, 1024, dmnG, cenG, fiN, Nx[0],Nx[1],Nx[2]);
    } else if (s==1){
      k_feat<144,0,0><<<BB*G, Tp, 0, stream>>>(xc, P[0],P[1],P[2], Cn[0],Cn[1],Cn[2], fiC, ki, ssum,
          n1, n2, N, G, lc, 0, 0, nullptr, nullptr, nullptr, nullptr, nullptr, nullptr);
    } else if (s==2){
      k_feat<288,0,0><<<BB*G, Tp, 0, stream>>>(xc, P[0],P[1],P[2], Cn[0],Cn[1],Cn[2], fiC, ki, ssum,
          n1, n2, N, G, lc, 0, 0, nullptr, nullptr, nullptr, nullptr, nullptr, nullptr);
    } else {
      k_feat<576,0,0><<<BB*G, Tp, 0, stream>>>(xc, P[0],P[1],P[2], Cn[0],Cn[1],Cn[2], fiC, ki, ssum,
          n1, n2, N, G, lc, 0, 0, nullptr, nullptr, nullptr, nullptr, nullptr, nullptr);
    }
    int M = BB*G;
    dim3 bng((D + 63)/64, NSTRIPE);
    k_bnpart<<<bng, 256, 0, stream>>>(lc, D, M, PSb, PQb);
    k_bnfin<<<(D + 63)/64, 64, 0, stream>>>(PSb, PQb, (const float*)d_in[2+2*s],
                                            (const float*)d_in[3+2*s], D, M, Abn, Bbn);
    int total = M*D;
    k_apply<<<(total+255)/256, 256, 0, stream>>>(lc, Abn, Bbn, D, total);
    float** t = P; P = Cn; Cn = Nx; Nx = t;
    int* ti = fiC; fiC = fiN; fiN = ti;
    float* tf = xc; xc = lc; lc = tf;
  }
  k_out<<<(BB*1152+255)/256, 256, 0, stream>>>(xc, (float*)d_out);
}

// Round 16
// 2624.678 us; speedup vs baseline: 1.0031x; 1.0031x over previous
//
#include <hip/hip_runtime.h>

typedef unsigned int u32;
typedef unsigned long long u64;
typedef float v2f __attribute__((ext_vector_type(2)));

#define BB 4
#define NP0 4096
#define KNB 90
#define CC0 72
#define MAXD 1152
#define NSTRIPE 16
#define FSPLIT 700   // FPS(1) split: [1,FSPLIT) in knnstd(0), [FSPLIT,1024) in feat(0)

// ---------------- fused input conversion (+ zero all per-stage sums) ----------------
__global__ void k_init(const float* __restrict__ xyz, const float* __restrict__ x,
                       float* __restrict__ xs, float* __restrict__ ys, float* __restrict__ zs,
                       float* __restrict__ feat, float* __restrict__ sums){
  int i = blockIdx.x*blockDim.x + threadIdx.x;
  if (i < 16) sums[i] = 0.f;
  if (i < BB*NP0){
    xs[i] = xyz[3*i+0];
    ys[i] = xyz[3*i+1];
    zs[i] = xyz[3*i+2];
  }
  if (i < BB*NP0*36){
    int j = i % 36; int bn = i / 36;
    int n = bn % NP0, b = bn / NP0;
    int cin = j / 12, f = j % 12;
    float xv = x[(b*3+cin)*NP0 + n];
    float rcp = __powf(1000.0f, -(float)f / 12.0f);
    float a = (100.0f * xv) * rcp;
    float sn, cs; __sincosf(a, &sn, &cs);
    float2 v = make_float2(sn, cs);
    *(float2*)(feat + (size_t)bn*CC0 + cin*24 + 2*f) = v;
  }
}

// Wave64 argmax: DPP fmax chain -> readlane(63) for max; ballot+ffs -> winning
// lane (smallest lane = smallest global index, jnp.argmax tie rule).
__device__ __forceinline__ void wave_argmax(float bd, int bi, float &smax, int &wbi){
  float v = bd;
  #define DPP_MAX(ctrl) do{ int _t = __builtin_amdgcn_mov_dpp(__float_as_int(v), (ctrl), 0xf, 0xf, true); \
                            v = fmaxf(v, __int_as_float(_t)); }while(0)
  DPP_MAX(0x111); DPP_MAX(0x112); DPP_MAX(0x114); DPP_MAX(0x118);
  DPP_MAX(0x142); DPP_MAX(0x143);
  #undef DPP_MAX
  smax = __int_as_float(__builtin_amdgcn_readlane(__float_as_int(v), 63));
  u64 msk = __ballot(bd == smax);
  int winlane = (int)__ffsll((long long)msk) - 1;
  wbi = __builtin_amdgcn_readlane(bi, winlane);
}

// ---------------- FPS stage 0 (standalone, exact, batch 0) ----------------
template<int PPT>
__global__ __launch_bounds__(256)
void k_fps4(const float* __restrict__ xs, const float* __restrict__ ys, const float* __restrict__ zs,
            int N, int G, int* __restrict__ fi,
            float* __restrict__ nxs, float* __restrict__ nys, float* __restrict__ nzs){
  constexpr int PH = PPT/2;
  __shared__ float4 sp[4096];
  __shared__ int sfi[2048];
  __shared__ u64 cand[2][4];
  int tid = threadIdx.x;
  const int base = tid * PPT;
  int wv = tid >> 6;
  int lane = tid & 63;
  v2f px[PH], py[PH], pz[PH], dmn[PH];
  #pragma unroll
  for (int j=0;j<PH;j++){
    int n = base + 2*j;
    float2 ax = *(const float2*)(xs+n);
    float2 ay = *(const float2*)(ys+n);
    float2 az = *(const float2*)(zs+n);
    px[j] = (v2f){ax.x, ax.y};
    py[j] = (v2f){ay.x, ay.y};
    pz[j] = (v2f){az.x, az.y};
    sp[n]   = make_float4(ax.x, ay.x, az.x, 0.f);
    sp[n+1] = make_float4(ax.y, ay.y, az.y, 0.f);
    dmn[j] = (v2f){INFINITY, INFINITY};
  }
  if (tid==0){ sfi[0]=0; }
  float lx = xs[0], ly = ys[0], lz = zs[0];
  __syncthreads();
  for (int t=1; t<G; t++){
    float bd = -INFINITY; int bi = base;
    v2f lx2 = (v2f){lx,lx}, ly2 = (v2f){ly,ly}, lz2 = (v2f){lz,lz};
    {
      #pragma clang fp contract(off)
      #pragma unroll
      for (int j=0;j<PH;j++){
        v2f dx = px[j] - lx2;
        v2f dy = py[j] - ly2;
        v2f dz = pz[j] - lz2;
        v2f d2 = (dx*dx + dy*dy) + dz*dz;
        v2f dmo = dmn[j];
        float dm0 = fminf(dmo.x, d2.x);
        float dm1 = fminf(dmo.y, d2.y);
        dmn[j] = (v2f){dm0, dm1};
        bool g0 = dm0 > bd;
        bd = g0 ? dm0 : bd;
        bi = g0 ? (base + 2*j) : bi;
        bool g1 = dm1 > bd;
        bd = g1 ? dm1 : bd;
        bi = g1 ? (base + 2*j + 1) : bi;
      }
    }
    float smax; int wbi;
    wave_argmax(bd, bi, smax, wbi);
    int par = t & 1;
    if (lane == 0) cand[par][wv] = ((u64)__float_as_uint(smax) << 32) | (u32)(~(u32)wbi);
    __syncthreads();
    u64 k0 = cand[par][0], k1 = cand[par][1], k2 = cand[par][2], k3 = cand[par][3];
    u64 ka = k0 > k1 ? k0 : k1;
    u64 kb = k2 > k3 ? k2 : k3;
    u64 km = ka > kb ? ka : kb;
    int w = (int)(~(u32)km);
    if ((u32)w >= (u32)N) w = 0;
    float4 p = sp[w];
    lx = p.x; ly = p.y; lz = p.z;
    if (tid==0){ sfi[t] = w; }
  }
  __syncthreads();
  for (int i = tid; i < G; i += 256) fi[i] = sfi[i];
  for (int i = tid; i < BB*G; i += 256){
    int b = i / G, g = i % G;
    int idx = sfi[g];
    nxs[i] = xs[(size_t)b*N + idx];
    nys[i] = ys[(size_t)b*N + idx];
    nzs[i] = zs[(size_t)b*N + idx];
  }
}

// ---------------- chunked FPS over current-stage centers ----------------
// Runs iterations [t0,t1) of FPS over the NF batch-0 centers. State across
// chunks: dmnG[NF] + cenG[0]. fi2[t] stored in-loop (global). Coords staged
// into LDS float4 (sp) at chunk start -> winner fetch is ONE ds_read_b128
// (R15 lesson: global winner reads cost ~+150 cyc/iter). If t1==NF/2, does
// the all-batch next-center gather. Tie rules identical to jnp.argmax.
template<int NF, int NT>
__device__ __forceinline__
void fps_chunk(const float* __restrict__ cxs, const float* __restrict__ cys, const float* __restrict__ czs,
               int t0, int t1,
               float* __restrict__ dmnG, float4* __restrict__ cenG,
               int* __restrict__ fi2,
               float* __restrict__ n2xs, float* __restrict__ n2ys, float* __restrict__ n2zs,
               u64 (&cand)[2][4], float4* __restrict__ sp){
  constexpr int PPT = NF/NT;
  constexpr int PH = PPT/2;
  constexpr int G2 = NF/2;
  constexpr int NW = NT/64;
  int tid = threadIdx.x;
  const int base = tid * PPT;
  int wv = tid >> 6, lane = tid & 63;
  v2f px[PH], py[PH], pz[PH], dmn[PH];
  #pragma unroll
  for (int j=0;j<PH;j++){
    int n = base + 2*j;
    float2 ax = *(const float2*)(cxs+n);
    float2 ay = *(const float2*)(cys+n);
    float2 az = *(const float2*)(czs+n);
    px[j] = (v2f){ax.x, ax.y};
    py[j] = (v2f){ay.x, ay.y};
    pz[j] = (v2f){az.x, az.y};
    sp[n]   = make_float4(ax.x, ay.x, az.x, 0.f);
    sp[n+1] = make_float4(ax.y, ay.y, az.y, 0.f);
  }
  float lx, ly, lz;
  if (t0 == 1){
    #pragma unroll
    for (int j=0;j<PH;j++) dmn[j] = (v2f){INFINITY, INFINITY};
    if (tid==0) fi2[0] = 0;
    lx = cxs[0]; ly = cys[0]; lz = czs[0];
  } else {
    #pragma unroll
    for (int j=0;j<PH;j++){
      float2 dv = *(const float2*)(dmnG + base + 2*j);
      dmn[j] = (v2f){dv.x, dv.y};
    }
    float4 c = *cenG;
    lx = c.x; ly = c.y; lz = c.z;
  }
  __syncthreads();  // sp staging visible
  for (int t=t0; t<t1; t++){
    float bd = -INFINITY; int bi = base;
    v2f lx2 = (v2f){lx,lx}, ly2 = (v2f){ly,ly}, lz2 = (v2f){lz,lz};
    {
      #pragma clang fp contract(off)
      #pragma unroll
      for (int j=0;j<PH;j++){
        v2f dx = px[j] - lx2;
        v2f dy = py[j] - ly2;
        v2f dz = pz[j] - lz2;
        v2f d2 = (dx*dx + dy*dy) + dz*dz;
        v2f dmo = dmn[j];
        float dm0 = fminf(dmo.x, d2.x);
        float dm1 = fminf(dmo.y, d2.y);
        dmn[j] = (v2f){dm0, dm1};
        bool g0 = dm0 > bd;
        bd = g0 ? dm0 : bd;
        bi = g0 ? (base + 2*j) : bi;
        bool g1 = dm1 > bd;
        bd = g1 ? dm1 : bd;
        bi = g1 ? (base + 2*j + 1) : bi;
      }
    }
    float smax; int wbi;
    wave_argmax(bd, bi, smax, wbi);
    int par = t & 1;
    if (lane == 0) cand[par][wv] = ((u64)__float_as_uint(smax) << 32) | (u32)(~(u32)wbi);
    __syncthreads();
    u64 km;
    if constexpr (NW >= 4){
      u64 k0 = cand[par][0], k1 = cand[par][1], k2 = cand[par][2], k3 = cand[par][3];
      u64 ka = k0 > k1 ? k0 : k1;
      u64 kb = k2 > k3 ? k2 : k3;
      km = ka > kb ? ka : kb;
    } else {
      u64 k0 = cand[par][0], k1 = cand[par][1];
      km = k0 > k1 ? k0 : k1;
    }
    int w = (int)(~(u32)km);
    if ((u32)w >= (u32)NF) w = 0;
    float4 p = sp[w];
    lx = p.x; ly = p.y; lz = p.z;
    if (tid==0) fi2[t] = w;
  }
  if (t1 < G2){
    #pragma unroll
    for (int j=0;j<PH;j++)
      *(float2*)(dmnG + base + 2*j) = make_float2(dmn[j].x, dmn[j].y);
    if (tid==0) *cenG = make_float4(lx, ly, lz, 0.f);
  } else {
    __syncthreads();  // drain fi2 stores; same-CU L1/L2 serves reads
    for (int i = tid; i < BB*G2; i += NT){
      int b2 = i / G2, g2 = i % G2;
      int idx = fi2[g2];
      if ((u32)idx >= (u32)NF) idx = 0;
      n2xs[i] = cxs[(size_t)b2*NF + idx];
      n2ys[i] = cys[(size_t)b2*NF + idx];
      n2zs[i] = czs[(size_t)b2*NF + idx];
    }
  }
}

// ---------------- fused kNN (exact radix select) + std partials + FPS chunk ----------------
__device__ float blockReduceSum(float v, float* sRed){
  for (int off=32; off; off>>=1) v += __shfl_down(v, off, 64);
  int wid = threadIdx.x >> 6, lane = threadIdx.x & 63;
  __syncthreads();
  if (lane==0) sRed[wid] = v;
  __syncthreads();
  float r = 0;
  if (threadIdx.x == 0){ for (int i=0;i<4;i++) r += sRed[i]; }
  return r;
}

template<int C, int NF>
__global__ __launch_bounds__(256)
void k_knnstd(const float* __restrict__ x,
              const float* __restrict__ xs, const float* __restrict__ ys, const float* __restrict__ zs,
              const float* __restrict__ nxs, const float* __restrict__ nys, const float* __restrict__ nzs,
              const int* __restrict__ fi, int N, int G,
              int* __restrict__ ki, float* __restrict__ sums,
              int t0, int t1, float* __restrict__ dmnG, float4* __restrict__ cenG,
              int* __restrict__ fi2, float* __restrict__ n2xs,
              float* __restrict__ n2ys, float* __restrict__ n2zs){
  extern __shared__ u32 smk[];
  __shared__ u64 candF[2][4];
  int tid = threadIdx.x;
  if constexpr (NF > 0){
    if (blockIdx.x == 0){
      fps_chunk<NF,256>(nxs, nys, nzs, t0, t1, dmnG, cenG, fi2, n2xs, n2ys, n2zs, candF, (float4*)smk);
      return;
    }
  }
  u32* keys = smk;           // N
  u32* hist = smk + N;       // 256
  u32* eq   = hist + 256;    // 512
  u32* sc   = eq + 512;      // [0]=prefix [1]=base [2]=outcnt [3]=eqcnt
  u32* wtot = sc + 4;        // 4 wave totals
  __shared__ float sLcx[C];
  __shared__ int sKi[KNB];
  __shared__ int sFi;
  __shared__ float sRed[4];
  int bid = (NF > 0) ? ((int)blockIdx.x - 1) : (int)blockIdx.x;
  int wv = tid >> 6, lane = tid & 63;
  int g = bid % G, b = bid / G;
  if (tid==0){ int f0 = fi[g]; if ((u32)f0 >= (u32)N) f0 = 0; sFi = f0; }
  float cx = nxs[b*G+g], cy = nys[b*G+g], cz = nzs[b*G+g];
  float ss = __fadd_rn(__fadd_rn(__fmul_rn(cx,cx), __fmul_rn(cy,cy)), __fmul_rn(cz,cz));
  for (int n = tid; n < N; n += 256){
    float px = xs[b*N+n], py = ys[b*N+n], pz = zs[b*N+n];
    float nn  = __fadd_rn(__fadd_rn(__fmul_rn(px,px), __fmul_rn(py,py)), __fmul_rn(pz,pz));
    float dot = __fadd_rn(__fadd_rn(__fmul_rn(cx,px), __fmul_rn(cy,py)), __fmul_rn(cz,pz));
    float sq  = __fsub_rn(__fadd_rn(ss, nn), __fmul_rn(2.0f, dot));
    u32 u = __float_as_uint(sq);
    keys[n] = (u & 0x80000000u) ? ~u : (u | 0x80000000u);
  }
  if (tid < 4) sc[tid] = 0;
  __syncthreads();
  for (int c = tid; c < C; c += 256) sLcx[c] = x[(size_t)(b*N + sFi)*C + c];
  u32 prefix = 0, bas = 0;
  for (int pass=0; pass<4; pass++){
    int shift = 24 - 8*pass;
    u32 mask = (pass==0) ? 0u : (0xFFFFFFFFu << (shift+8));
    hist[tid] = 0;
    __syncthreads();
    for (int n = tid; n < N; n += 256){
      u32 k = keys[n];
      if ((k & mask) == (prefix & mask))
        atomicAdd(&hist[(k >> shift) & 255u], 1u);
    }
    __syncthreads();
    u32 h = hist[tid];
    u32 p = h;
    #pragma unroll
    for (int off=1; off<64; off<<=1){
      u32 o = __shfl_up(p, off, 64);
      if (lane >= off) p += o;
    }
    if (lane == 63) wtot[wv] = p;
    __syncthreads();
    u32 ex = p - h;
    for (int w2=0; w2<wv; w2++) ex += wtot[w2];
    if (bas + ex < KNB && bas + ex + h >= KNB){
      sc[0] = prefix | ((u32)tid << shift);
      sc[1] = bas + ex;
    }
    __syncthreads();
    prefix = sc[0]; bas = sc[1];
    __syncthreads();
  }
  u32 T = prefix;
  int needEq = KNB - (int)bas;
  int* out = ki + (size_t)(b*G+g)*KNB;
  for (int n = tid; n < N; n += 256){
    u32 k = keys[n];
    if (k < T){
      u32 p2 = atomicAdd(&sc[2], 1u);
      if (p2 < KNB){ out[p2] = n; sKi[p2] = n; }
    } else if (k == T){
      u32 e = atomicAdd(&sc[3], 1u);
      if (e < 512) eq[e] = (u32)n;
    }
  }
  __syncthreads();
  int m = (int)sc[3]; if (m > 512) m = 512;
  for (int i = tid; i < m; i += 256){
    u32 v = eq[i];
    int r = 0;
    for (int j=0; j<m; j++) r += (eq[j] < v);
    if (r < needEq){
      u32 p2 = atomicAdd(&sc[2], 1u);
      if (p2 < KNB){ out[p2] = (int)v; sKi[p2] = (int)v; }
    }
  }
  __syncthreads();
  if (tid == 0){
    u32 c = sc[2];
    while (c < KNB){ out[c] = 0; sKi[c] = 0; c++; }
  }
  __syncthreads();
  float s1=0, s2=0, s3=0, s4=0;
  constexpr int C2 = C/2;
  for (int u2 = tid; u2 < KNB*C2; u2 += 256){
    int k = u2 / C2; int c = (u2 - k*C2)*2;
    int idx = sKi[k];
    float2 v = *(const float2*)(x + (size_t)(b*N + idx)*C + c);
    float a0 = v.x - sLcx[c];
    float a1 = v.y - sLcx[c+1];
    s1 += a0 + a1; s2 += a0*a0 + a1*a1;
  }
  if (tid < 3){
    for (int k=0;k<KNB;k++){
      int idx = sKi[k];
      float pc = (tid==0 ? xs[b*N+idx] : tid==1 ? ys[b*N+idx] : zs[b*N+idx]);
      float cc = (tid==0 ? cx : tid==1 ? cy : cz);
      float w = pc - cc;
      s3 += w; s4 += w*w;
    }
  }
  float t;
  t = blockReduceSum(s1, sRed); if (tid==0) atomicAdd(&sums[0], t);
  t = blockReduceSum(s2, sRed); if (tid==0) atomicAdd(&sums[1], t);
  t = blockReduceSum(s3, sRed); if (tid==0) atomicAdd(&sums[2], t);
  t = blockReduceSum(s4, sRed); if (tid==0) atomicAdd(&sums[3], t);
}

// ---------------- main feature kernel (+ optional FPS chunk in block 0) ----------------
template<int C, int NF, int NT>
__global__ void k_feat(const float* __restrict__ x,
            const float* __restrict__ xs, const float* __restrict__ ys, const float* __restrict__ zs,
            const float* __restrict__ nxs, const float* __restrict__ nys, const float* __restrict__ nzs,
            const int* __restrict__ fi, const int* __restrict__ ki, const float* __restrict__ sums,
            double n1, double n2,
            int N, int G, float* __restrict__ lc,
            int t0, int t1, float* __restrict__ dmnG, float4* __restrict__ cenG,
            int* __restrict__ fi2, float* __restrict__ n2xs,
            float* __restrict__ n2ys, float* __restrict__ n2zs){
  constexpr int D = 2*C;
  constexpr int D3 = D/3;
  constexpr int FD = C/3;
  extern __shared__ u32 smf[];
  __shared__ u64 candF[2][4];
  __shared__ float sLcx[C];
  __shared__ float sDx[KNB*3];
  __shared__ int sKi[KNB];
  __shared__ int sFi;
  __shared__ float sC[3];
  __shared__ float sInv2[2];
  int tid = threadIdx.x;
  if constexpr (NF > 0){
    if (blockIdx.x == 0){
      fps_chunk<NF,NT>(nxs, nys, nzs, t0, t1, dmnG, cenG, fi2, n2xs, n2ys, n2zs, candF, (float4*)smf);
      return;
    }
  }
  int bid = (NF > 0) ? ((int)blockIdx.x - 1) : (int)blockIdx.x;
  int g = bid % G, b = bid / G;
  if (tid==0){ int f0 = fi[g]; if ((u32)f0 >= (u32)N) f0 = 0; sFi = f0; }
  if (tid==0){
    double s1 = sums[0], s2 = sums[1];
    double mean = s1/n1;
    double var = (s2 - s1*mean)/(n1 - 1.0); if (var < 0) var = 0;
    sInv2[0] = (float)(1.0/(sqrt(var) + 1e-5));
    double t1d = sums[2], t2d = sums[3];
    double m2 = t1d/n2;
    double v2 = (t2d - t1d*m2)/(n2 - 1.0); if (v2 < 0) v2 = 0;
    sInv2[1] = (float)(1.0/(sqrt(v2) + 1e-5));
  }
  if (tid<3) sC[tid] = (tid==0 ? nxs[b*G+g] : tid==1 ? nys[b*G+g] : nzs[b*G+g]);
  if (tid < KNB){ int v = ki[(size_t)(b*G+g)*KNB + tid]; if ((u32)v >= (u32)N) v = 0; sKi[tid] = v; }
  __syncthreads();
  for (int c = tid; c < C; c += blockDim.x) sLcx[c] = x[(size_t)(b*N + sFi)*C + c];
  for (int t = tid; t < KNB*3; t += blockDim.x){
    int k = t/3, c = t%3;
    int idx = sKi[k];
    float pc = (c==0 ? xs[b*N+idx] : c==1 ? ys[b*N+idx] : zs[b*N+idx]);
    sDx[t] = (pc - sC[c]) * sInv2[1];
  }
  __syncthreads();
  int p = tid;
  if (p >= C) return;
  int d0 = 2*p;
  int c = d0 / D3;
  int f = (d0 - c*D3) >> 1;
  float rcp = __powf(1000.0f, -(float)f / (float)FD);
  bool low = (d0 < C);
  float invdx = sInv2[0];
  float fh0 = 0.f, fh1 = 0.f;
  if (!low){ fh0 = sLcx[d0-C]; fh1 = sLcx[d0+1-C]; }
  float l0 = low ? sLcx[d0] : 0.f, l1 = low ? sLcx[d0+1] : 0.f;
  float mx0=-INFINITY, mx1=-INFINITY, sm0=0.f, sm1=0.f;
  for (int k=0;k<KNB;k++){
    float a = (100.0f * sDx[k*3+c]) * rcp;
    float sn, cs; __sincosf(a, &sn, &cs);
    float f0, f1;
    if (low){
      float2 v = *(const float2*)(x + (size_t)(b*N + sKi[k])*C + d0);
      f0 = (v.x - l0) * invdx;
      f1 = (v.y - l1) * invdx;
    } else { f0 = fh0; f1 = fh1; }
    float w0 = (f0 + sn)*sn;
    float w1 = (f1 + cs)*cs;
    mx0 = fmaxf(mx0, w0); sm0 += w0;
    mx1 = fmaxf(mx1, w1); sm1 += w1;
  }
  float* o = lc + (size_t)(b*G+g)*D + d0;
  o[0] = mx0 + sm0/90.0f;
  o[1] = mx1 + sm1/90.0f;
}

// ---------------- BatchNorm: parallel partial stats ----------------
__global__ __launch_bounds__(256)
void k_bnpart(const float* __restrict__ lc, int D, int M,
              double* __restrict__ PS, double* __restrict__ PQ){
  __shared__ double sS[4][64], sQ[4][64];
  int lane = threadIdx.x & 63, row = threadIdx.x >> 6;
  int tile = blockIdx.x, stripe = blockIdx.y;
  int d = tile*64 + lane;
  int span = M / NSTRIPE;
  int i0 = stripe * span;
  double s=0, q=0;
  if (d < D){
    for (int i=i0+row; i<i0+span; i+=4){
      float v = lc[(size_t)i*D + d];
      s += v; q += (double)v*v;
    }
  }
  sS[row][lane]=s; sQ[row][lane]=q;
  __syncthreads();
  if (row==0 && d < D){
    PS[(size_t)stripe*MAXD + d] = sS[0][lane]+sS[1][lane]+sS[2][lane]+sS[3][lane];
    PQ[(size_t)stripe*MAXD + d] = sQ[0][lane]+sQ[1][lane]+sQ[2][lane]+sQ[3][lane];
  }
}

__global__ void k_bnfin(const double* __restrict__ PS, const double* __restrict__ PQ,
                        const float* __restrict__ gamma, const float* __restrict__ beta,
                        int D, int M, float* __restrict__ A, float* __restrict__ Bb){
  int d = blockIdx.x*64 + threadIdx.x;
  if (d >= D) return;
  double ts=0, tq=0;
  for (int s=0; s<NSTRIPE; s++){ ts += PS[(size_t)s*MAXD + d]; tq += PQ[(size_t)s*MAXD + d]; }
  double mean = ts / M;
  double var = tq / M - mean*mean; if (var < 0) var = 0;
  float rstd = (float)(1.0/sqrt(var + 1e-5));
  float gm = gamma[d], bt = beta[d];
  A[d] = gm*rstd;
  Bb[d] = bt - (float)mean*gm*rstd;
}

// in-place BN + GELU — large coalesced grid
__global__ void k_apply(float* __restrict__ lc, const float* __restrict__ A,
                        const float* __restrict__ Bb, int D, int total){
  int i = blockIdx.x*blockDim.x + threadIdx.x;
  if (i >= total) return;
  int d = i % D;
  float v = lc[i]*A[d] + Bb[d];
  lc[i] = 0.5f * v * (1.0f + erff(v * 0.70710678118654752f));
}

__global__ void k_out(const float* __restrict__ feat, float* __restrict__ out){
  int i = blockIdx.x*blockDim.x + threadIdx.x;
  if (i >= BB*1152) return;
  int b = i / 1152, d = i % 1152;
  const float* base = feat + (size_t)b*256*1152 + d;
  float mx = -INFINITY, sm = 0.f;
  for (int g=0; g<256; g++){
    float v = base[(size_t)g*1152];
    mx = fmaxf(mx, v); sm += v;
  }
  out[i] = mx + sm/256.0f;
}

// ---------------- launch ----------------
extern "C" void kernel_launch(void* const* d_in, const int* in_sizes, int n_in,
                              void* d_out, int out_size, void* d_ws, size_t ws_size,
                              hipStream_t stream) {
  const float* xyz = (const float*)d_in[0];
  const float* xin = (const float*)d_in[1];
  float* ws = (float*)d_ws;
  size_t off = 0;
  const size_t PS_ = (size_t)BB*NP0;
  const size_t XS = (size_t)BB*NP0*CC0;
  float* T0[3]; float* T1[3]; float* T2[3];
  for (int i=0;i<3;i++){ T0[i] = ws + off; off += PS_; }
  for (int i=0;i<3;i++){ T1[i] = ws + off; off += PS_; }
  for (int i=0;i<3;i++){ T2[i] = ws + off; off += PS_; }
  float* xA = ws + off; off += XS;
  float* xB = ws + off; off += XS;
  int*   fiA = (int*)(ws + off); off += 2048;
  int*   fiB = (int*)(ws + off); off += 2048;
  int*   ki = (int*)(ws + off); off += (size_t)BB*2048*KNB;
  float* sums = ws + off; off += 16;
  float* Abn  = ws + off; off += 1152;
  float* Bbn  = ws + off; off += 1152;
  float* dmnG = ws + off; off += 2048;
  float4* cenG = (float4*)(ws + off); off += 4;
  off = (off + 1) & ~(size_t)1;
  double* PSb = (double*)(ws + off); off += (size_t)NSTRIPE*MAXD*2;
  double* PQb = (double*)(ws + off); off += (size_t)NSTRIPE*MAXD*2;

  k_init<<<(BB*NP0*36+255)/256, 256, 0, stream>>>(xyz, xin, T0[0], T0[1], T0[2], xA, sums);
  k_fps4<16><<<1, 256, 0, stream>>>(T0[0],T0[1],T0[2], NP0, NP0/2, fiA, T1[0],T1[1],T1[2]);

  float **P = T0, **Cn = T1, **Nx = T2;
  int *fiC = fiA, *fiN = fiB;
  float *xc = xA, *lc = xB;
  for (int s=0; s<4; s++){
    int N = NP0 >> s, G = N >> 1, C = CC0 << s, D = 2*C;
    float* ssum = sums + 4*s;
    size_t knn_need = (size_t)(N + 256 + 512 + 8 + 8)*4;
    if (s==0){
      size_t lds = knn_need; size_t fps_need = (size_t)2048*16;
      if (fps_need > lds) lds = fps_need;
      // FPS(1) chunk A: iters [1, FSPLIT)
      k_knnstd<72,2048><<<BB*G+1, 256, lds, stream>>>(xc, P[0],P[1],P[2], Cn[0],Cn[1],Cn[2],
          fiC, N, G, ki, ssum, 1, FSPLIT, dmnG, cenG, fiN, Nx[0],Nx[1],Nx[2]);
    } else if (s==1){
      size_t lds = knn_need; size_t fps_need = (size_t)1024*16;
      if (fps_need > lds) lds = fps_need;
      k_knnstd<144,1024><<<BB*G+1, 256, lds, stream>>>(xc, P[0],P[1],P[2], Cn[0],Cn[1],Cn[2],
          fiC, N, G, ki, ssum, 1, 512, dmnG, cenG, fiN, Nx[0],Nx[1],Nx[2]);
    } else if (s==2){
      size_t lds = knn_need; size_t fps_need = (size_t)512*16;
      if (fps_need > lds) lds = fps_need;
      k_knnstd<288,512><<<BB*G+1, 256, lds, stream>>>(xc, P[0],P[1],P[2], Cn[0],Cn[1],Cn[2],
          fiC, N, G, ki, ssum, 1, 256, dmnG, cenG, fiN, Nx[0],Nx[1],Nx[2]);
    } else {
      k_knnstd<576,0><<<BB*G, 256, knn_need, stream>>>(xc, P[0],P[1],P[2], Cn[0],Cn[1],Cn[2],
          fiC, N, G, ki, ssum, 0, 0, nullptr, nullptr, nullptr, nullptr, nullptr, nullptr);
    }
    double n1 = (double)BB*G*KNB*C, n2 = (double)BB*G*KNB*3;
    int Tp = ((C + 63)/64)*64;
    if (s==0){
      // FPS(1) chunk B: iters [FSPLIT, 1024) + gather, block 0 of feat
      k_feat<72,2048,128><<<BB*G+1, Tp, (size_t)2048*16, stream>>>(xc, P[0],P[1],P[2], Cn[0],Cn[1],Cn[2], fiC, ki, ssum,
          n1, n2, N, G, lc, FSPLIT, 1024, dmnG, cenG, fiN, Nx[0],Nx[1],Nx[2]);
    } else if (s==1){
      k_feat<144,0,0><<<BB*G, Tp, 0, stream>>>(xc, P[0],P[1],P[2], Cn[0],Cn[1],Cn[2], fiC, ki, ssum,
          n1, n2, N, G, lc, 0, 0, nullptr, nullptr, nullptr, nullptr, nullptr, nullptr);
    } else if (s==2){
      k_feat<288,0,0><<<BB*G, Tp, 0, stream>>>(xc, P[0],P[1],P[2], Cn[0],Cn[1],Cn[2], fiC, ki, ssum,
          n1, n2, N, G, lc, 0, 0, nullptr, nullptr, nullptr, nullptr, nullptr, nullptr);
    } else {
      k_feat<576,0,0><<<BB*G, Tp, 0, stream>>>(xc, P[0],P[1],P[2], Cn[0],Cn[1],Cn[2], fiC, ki, ssum,
          n1, n2, N, G, lc, 0, 0, nullptr, nullptr, nullptr, nullptr, nullptr, nullptr);
    }
    int M = BB*G;
    dim3 bng((D + 63)/64, NSTRIPE);
    k_bnpart<<<bng, 256, 0, stream>>>(lc, D, M, PSb, PQb);
    k_bnfin<<<(D + 63)/64, 64, 0, stream>>>(PSb, PQb, (const float*)d_in[2+2*s],
                                            (const float*)d_in[3+2*s], D, M, Abn, Bbn);
    int total = M*D;
    k_apply<<<(total+255)/256, 256, 0, stream>>>(lc, Abn, Bbn, D, total);
    float** t = P; P = Cn; Cn = Nx; Nx = t;
    int* ti = fiC; fiC = fiN; fiN = ti;
    float* tf = xc; xc = lc; lc = tf;
  }
  k_out<<<(BB*1152+255)/256, 256, 0, stream>>>(xc, (float*)d_out);
}

// Round 17
// 2530.558 us; speedup vs baseline: 1.0404x; 1.0372x over previous
//
#include <hip/hip_runtime.h>

typedef unsigned int u32;
typedef unsigned long long u64;
typedef float v2f __attribute__((ext_vector_type(2)));

#define BB 4
#define NP0 4096
#define KNB 90
#define CC0 72
#define MAXD 1152
#define NSTRIPE 16
#define FSPLIT 850   // FPS(1) split: [1,FSPLIT) in knnstd(0) (LDS), [FSPLIT,1024) in feat(0) (global)

// ---------------- fused input conversion (+ zero all per-stage sums) ----------------
__global__ void k_init(const float* __restrict__ xyz, const float* __restrict__ x,
                       float* __restrict__ xs, float* __restrict__ ys, float* __restrict__ zs,
                       float* __restrict__ feat, float* __restrict__ sums){
  int i = blockIdx.x*blockDim.x + threadIdx.x;
  if (i < 16) sums[i] = 0.f;
  if (i < BB*NP0){
    xs[i] = xyz[3*i+0];
    ys[i] = xyz[3*i+1];
    zs[i] = xyz[3*i+2];
  }
  if (i < BB*NP0*36){
    int j = i % 36; int bn = i / 36;
    int n = bn % NP0, b = bn / NP0;
    int cin = j / 12, f = j % 12;
    float xv = x[(b*3+cin)*NP0 + n];
    float rcp = __powf(1000.0f, -(float)f / 12.0f);
    float a = (100.0f * xv) * rcp;
    float sn, cs; __sincosf(a, &sn, &cs);
    float2 v = make_float2(sn, cs);
    *(float2*)(feat + (size_t)bn*CC0 + cin*24 + 2*f) = v;
  }
}

// Wave64 argmax: DPP fmax chain -> readlane(63) for max; ballot+ffs -> winning
// lane (smallest lane = smallest global index, jnp.argmax tie rule).
__device__ __forceinline__ void wave_argmax(float bd, int bi, float &smax, int &wbi){
  float v = bd;
  #define DPP_MAX(ctrl) do{ int _t = __builtin_amdgcn_mov_dpp(__float_as_int(v), (ctrl), 0xf, 0xf, true); \
                            v = fmaxf(v, __int_as_float(_t)); }while(0)
  DPP_MAX(0x111); DPP_MAX(0x112); DPP_MAX(0x114); DPP_MAX(0x118);
  DPP_MAX(0x142); DPP_MAX(0x143);
  #undef DPP_MAX
  smax = __int_as_float(__builtin_amdgcn_readlane(__float_as_int(v), 63));
  u64 msk = __ballot(bd == smax);
  int winlane = (int)__ffsll((long long)msk) - 1;
  wbi = __builtin_amdgcn_readlane(bi, winlane);
}

// ---------------- FPS stage 0 (standalone, exact, batch 0) ----------------
template<int PPT>
__global__ __launch_bounds__(256)
void k_fps4(const float* __restrict__ xs, const float* __restrict__ ys, const float* __restrict__ zs,
            int N, int G, int* __restrict__ fi,
            float* __restrict__ nxs, float* __restrict__ nys, float* __restrict__ nzs){
  constexpr int PH = PPT/2;
  __shared__ float4 sp[4096];
  __shared__ int sfi[2048];
  __shared__ u64 cand[2][4];
  int tid = threadIdx.x;
  const int base = tid * PPT;
  int wv = tid >> 6;
  int lane = tid & 63;
  v2f px[PH], py[PH], pz[PH], dmn[PH];
  #pragma unroll
  for (int j=0;j<PH;j++){
    int n = base + 2*j;
    float2 ax = *(const float2*)(xs+n);
    float2 ay = *(const float2*)(ys+n);
    float2 az = *(const float2*)(zs+n);
    px[j] = (v2f){ax.x, ax.y};
    py[j] = (v2f){ay.x, ay.y};
    pz[j] = (v2f){az.x, az.y};
    sp[n]   = make_float4(ax.x, ay.x, az.x, 0.f);
    sp[n+1] = make_float4(ax.y, ay.y, az.y, 0.f);
    dmn[j] = (v2f){INFINITY, INFINITY};
  }
  if (tid==0){ sfi[0]=0; }
  float lx = xs[0], ly = ys[0], lz = zs[0];
  __syncthreads();
  for (int t=1; t<G; t++){
    float bd = -INFINITY; int bi = base;
    v2f lx2 = (v2f){lx,lx}, ly2 = (v2f){ly,ly}, lz2 = (v2f){lz,lz};
    {
      #pragma clang fp contract(off)
      #pragma unroll
      for (int j=0;j<PH;j++){
        v2f dx = px[j] - lx2;
        v2f dy = py[j] - ly2;
        v2f dz = pz[j] - lz2;
        v2f d2 = (dx*dx + dy*dy) + dz*dz;
        v2f dmo = dmn[j];
        float dm0 = fminf(dmo.x, d2.x);
        float dm1 = fminf(dmo.y, d2.y);
        dmn[j] = (v2f){dm0, dm1};
        bool g0 = dm0 > bd;
        bd = g0 ? dm0 : bd;
        bi = g0 ? (base + 2*j) : bi;
        bool g1 = dm1 > bd;
        bd = g1 ? dm1 : bd;
        bi = g1 ? (base + 2*j + 1) : bi;
      }
    }
    float smax; int wbi;
    wave_argmax(bd, bi, smax, wbi);
    int par = t & 1;
    if (lane == 0) cand[par][wv] = ((u64)__float_as_uint(smax) << 32) | (u32)(~(u32)wbi);
    __syncthreads();
    u64 k0 = cand[par][0], k1 = cand[par][1], k2 = cand[par][2], k3 = cand[par][3];
    u64 ka = k0 > k1 ? k0 : k1;
    u64 kb = k2 > k3 ? k2 : k3;
    u64 km = ka > kb ? ka : kb;
    int w = (int)(~(u32)km);
    if ((u32)w >= (u32)N) w = 0;
    float4 p = sp[w];
    lx = p.x; ly = p.y; lz = p.z;
    if (tid==0){ sfi[t] = w; }
  }
  __syncthreads();
  for (int i = tid; i < G; i += 256) fi[i] = sfi[i];
  for (int i = tid; i < BB*G; i += 256){
    int b = i / G, g = i % G;
    int idx = sfi[g];
    nxs[i] = xs[(size_t)b*N + idx];
    nys[i] = ys[(size_t)b*N + idx];
    nzs[i] = zs[(size_t)b*N + idx];
  }
}

// ---------------- chunked FPS over current-stage centers ----------------
// Iterations [t0,t1) of FPS over NF batch-0 centers. State across chunks:
// dmnG[NF] + cenG[0]; fi2[t] stored in-loop. LDSST=true: coords staged to LDS
// float4, winner fetch = 1 ds_read_b128 (fast path; costs dyn-LDS on the host
// grid). LDSST=false: winner coords from global (~+0.15us/iter) but ZERO
// dynamic LDS — use where host-kernel occupancy matters (R16 lesson).
template<int NF, int NT, bool LDSST>
__device__ __forceinline__
void fps_chunk(const float* __restrict__ cxs, const float* __restrict__ cys, const float* __restrict__ czs,
               int t0, int t1,
               float* __restrict__ dmnG, float4* __restrict__ cenG,
               int* __restrict__ fi2,
               float* __restrict__ n2xs, float* __restrict__ n2ys, float* __restrict__ n2zs,
               u64 (&cand)[2][4], float4* __restrict__ sp){
  constexpr int PPT = NF/NT;
  constexpr int PH = PPT/2;
  constexpr int G2 = NF/2;
  constexpr int NW = NT/64;
  int tid = threadIdx.x;
  const int base = tid * PPT;
  int wv = tid >> 6, lane = tid & 63;
  v2f px[PH], py[PH], pz[PH], dmn[PH];
  #pragma unroll
  for (int j=0;j<PH;j++){
    int n = base + 2*j;
    float2 ax = *(const float2*)(cxs+n);
    float2 ay = *(const float2*)(cys+n);
    float2 az = *(const float2*)(czs+n);
    px[j] = (v2f){ax.x, ax.y};
    py[j] = (v2f){ay.x, ay.y};
    pz[j] = (v2f){az.x, az.y};
    if constexpr (LDSST){
      sp[n]   = make_float4(ax.x, ay.x, az.x, 0.f);
      sp[n+1] = make_float4(ax.y, ay.y, az.y, 0.f);
    }
  }
  float lx, ly, lz;
  if (t0 == 1){
    #pragma unroll
    for (int j=0;j<PH;j++) dmn[j] = (v2f){INFINITY, INFINITY};
    if (tid==0) fi2[0] = 0;
    lx = cxs[0]; ly = cys[0]; lz = czs[0];
  } else {
    #pragma unroll
    for (int j=0;j<PH;j++){
      float2 dv = *(const float2*)(dmnG + base + 2*j);
      dmn[j] = (v2f){dv.x, dv.y};
    }
    float4 c = *cenG;
    lx = c.x; ly = c.y; lz = c.z;
  }
  __syncthreads();
  for (int t=t0; t<t1; t++){
    float bd = -INFINITY; int bi = base;
    v2f lx2 = (v2f){lx,lx}, ly2 = (v2f){ly,ly}, lz2 = (v2f){lz,lz};
    {
      #pragma clang fp contract(off)
      #pragma unroll
      for (int j=0;j<PH;j++){
        v2f dx = px[j] - lx2;
        v2f dy = py[j] - ly2;
        v2f dz = pz[j] - lz2;
        v2f d2 = (dx*dx + dy*dy) + dz*dz;
        v2f dmo = dmn[j];
        float dm0 = fminf(dmo.x, d2.x);
        float dm1 = fminf(dmo.y, d2.y);
        dmn[j] = (v2f){dm0, dm1};
        bool g0 = dm0 > bd;
        bd = g0 ? dm0 : bd;
        bi = g0 ? (base + 2*j) : bi;
        bool g1 = dm1 > bd;
        bd = g1 ? dm1 : bd;
        bi = g1 ? (base + 2*j + 1) : bi;
      }
    }
    float smax; int wbi;
    wave_argmax(bd, bi, smax, wbi);
    int par = t & 1;
    if (lane == 0) cand[par][wv] = ((u64)__float_as_uint(smax) << 32) | (u32)(~(u32)wbi);
    __syncthreads();
    u64 km;
    if constexpr (NW >= 4){
      u64 k0 = cand[par][0], k1 = cand[par][1], k2 = cand[par][2], k3 = cand[par][3];
      u64 ka = k0 > k1 ? k0 : k1;
      u64 kb = k2 > k3 ? k2 : k3;
      km = ka > kb ? ka : kb;
    } else {
      u64 k0 = cand[par][0], k1 = cand[par][1];
      km = k0 > k1 ? k0 : k1;
    }
    int w = (int)(~(u32)km);
    if ((u32)w >= (u32)NF) w = 0;
    if constexpr (LDSST){
      float4 p = sp[w];
      lx = p.x; ly = p.y; lz = p.z;
    } else {
      lx = cxs[w]; ly = cys[w]; lz = czs[w];
    }
    if (tid==0) fi2[t] = w;
  }
  if (t1 < G2){
    #pragma unroll
    for (int j=0;j<PH;j++)
      *(float2*)(dmnG + base + 2*j) = make_float2(dmn[j].x, dmn[j].y);
    if (tid==0) *cenG = make_float4(lx, ly, lz, 0.f);
  } else {
    __syncthreads();  // drain fi2 stores; same-CU L1/L2 serves reads
    for (int i = tid; i < BB*G2; i += NT){
      int b2 = i / G2, g2 = i % G2;
      int idx = fi2[g2];
      if ((u32)idx >= (u32)NF) idx = 0;
      n2xs[i] = cxs[(size_t)b2*NF + idx];
      n2ys[i] = cys[(size_t)b2*NF + idx];
      n2zs[i] = czs[(size_t)b2*NF + idx];
    }
  }
}

// ---------------- fused kNN (exact radix select) + std partials + FPS chunk ----------------
__device__ float blockReduceSum(float v, float* sRed){
  for (int off=32; off; off>>=1) v += __shfl_down(v, off, 64);
  int wid = threadIdx.x >> 6, lane = threadIdx.x & 63;
  __syncthreads();
  if (lane==0) sRed[wid] = v;
  __syncthreads();
  float r = 0;
  if (threadIdx.x == 0){ for (int i=0;i<4;i++) r += sRed[i]; }
  return r;
}

template<int C, int NF>
__global__ __launch_bounds__(256)
void k_knnstd(const float* __restrict__ x,
              const float* __restrict__ xs, const float* __restrict__ ys, const float* __restrict__ zs,
              const float* __restrict__ nxs, const float* __restrict__ nys, const float* __restrict__ nzs,
              const int* __restrict__ fi, int N, int G,
              int* __restrict__ ki, float* __restrict__ sums,
              int t0, int t1, float* __restrict__ dmnG, float4* __restrict__ cenG,
              int* __restrict__ fi2, float* __restrict__ n2xs,
              float* __restrict__ n2ys, float* __restrict__ n2zs){
  extern __shared__ u32 smk[];
  __shared__ u64 candF[2][4];
  int tid = threadIdx.x;
  if constexpr (NF > 0){
    if (blockIdx.x == 0){
      fps_chunk<NF,256,true>(nxs, nys, nzs, t0, t1, dmnG, cenG, fi2, n2xs, n2ys, n2zs, candF, (float4*)smk);
      return;
    }
  }
  u32* keys = smk;           // N
  u32* hist = smk + N;       // 256
  u32* eq   = hist + 256;    // 512
  u32* sc   = eq + 512;      // [0]=prefix [1]=base [2]=outcnt [3]=eqcnt
  u32* wtot = sc + 4;        // 4 wave totals
  __shared__ float sLcx[C];
  __shared__ int sKi[KNB];
  __shared__ int sFi;
  __shared__ float sRed[4];
  int bid = (NF > 0) ? ((int)blockIdx.x - 1) : (int)blockIdx.x;
  int wv = tid >> 6, lane = tid & 63;
  int g = bid % G, b = bid / G;
  if (tid==0){ int f0 = fi[g]; if ((u32)f0 >= (u32)N) f0 = 0; sFi = f0; }
  float cx = nxs[b*G+g], cy = nys[b*G+g], cz = nzs[b*G+g];
  float ss = __fadd_rn(__fadd_rn(__fmul_rn(cx,cx), __fmul_rn(cy,cy)), __fmul_rn(cz,cz));
  for (int n = tid; n < N; n += 256){
    float px = xs[b*N+n], py = ys[b*N+n], pz = zs[b*N+n];
    float nn  = __fadd_rn(__fadd_rn(__fmul_rn(px,px), __fmul_rn(py,py)), __fmul_rn(pz,pz));
    float dot = __fadd_rn(__fadd_rn(__fmul_rn(cx,px), __fmul_rn(cy,py)), __fmul_rn(cz,pz));
    float sq  = __fsub_rn(__fadd_rn(ss, nn), __fmul_rn(2.0f, dot));
    u32 u = __float_as_uint(sq);
    keys[n] = (u & 0x80000000u) ? ~u : (u | 0x80000000u);
  }
  if (tid < 4) sc[tid] = 0;
  __syncthreads();
  for (int c = tid; c < C; c += 256) sLcx[c] = x[(size_t)(b*N + sFi)*C + c];
  u32 prefix = 0, bas = 0;
  for (int pass=0; pass<4; pass++){
    int shift = 24 - 8*pass;
    u32 mask = (pass==0) ? 0u : (0xFFFFFFFFu << (shift+8));
    hist[tid] = 0;
    __syncthreads();
    for (int n = tid; n < N; n += 256){
      u32 k = keys[n];
      if ((k & mask) == (prefix & mask))
        atomicAdd(&hist[(k >> shift) & 255u], 1u);
    }
    __syncthreads();
    u32 h = hist[tid];
    u32 p = h;
    #pragma unroll
    for (int off=1; off<64; off<<=1){
      u32 o = __shfl_up(p, off, 64);
      if (lane >= off) p += o;
    }
    if (lane == 63) wtot[wv] = p;
    __syncthreads();
    u32 ex = p - h;
    for (int w2=0; w2<wv; w2++) ex += wtot[w2];
    if (bas + ex < KNB && bas + ex + h >= KNB){
      sc[0] = prefix | ((u32)tid << shift);
      sc[1] = bas + ex;
    }
    __syncthreads();
    prefix = sc[0]; bas = sc[1];
    __syncthreads();
  }
  u32 T = prefix;
  int needEq = KNB - (int)bas;
  int* out = ki + (size_t)(b*G+g)*KNB;
  for (int n = tid; n < N; n += 256){
    u32 k = keys[n];
    if (k < T){
      u32 p2 = atomicAdd(&sc[2], 1u);
      if (p2 < KNB){ out[p2] = n; sKi[p2] = n; }
    } else if (k == T){
      u32 e = atomicAdd(&sc[3], 1u);
      if (e < 512) eq[e] = (u32)n;
    }
  }
  __syncthreads();
  int m = (int)sc[3]; if (m > 512) m = 512;
  for (int i = tid; i < m; i += 256){
    u32 v = eq[i];
    int r = 0;
    for (int j=0; j<m; j++) r += (eq[j] < v);
    if (r < needEq){
      u32 p2 = atomicAdd(&sc[2], 1u);
      if (p2 < KNB){ out[p2] = (int)v; sKi[p2] = (int)v; }
    }
  }
  __syncthreads();
  if (tid == 0){
    u32 c = sc[2];
    while (c < KNB){ out[c] = 0; sKi[c] = 0; c++; }
  }
  __syncthreads();
  float s1=0, s2=0, s3=0, s4=0;
  constexpr int C2 = C/2;
  for (int u2 = tid; u2 < KNB*C2; u2 += 256){
    int k = u2 / C2; int c = (u2 - k*C2)*2;
    int idx = sKi[k];
    float2 v = *(const float2*)(x + (size_t)(b*N + idx)*C + c);
    float a0 = v.x - sLcx[c];
    float a1 = v.y - sLcx[c+1];
    s1 += a0 + a1; s2 += a0*a0 + a1*a1;
  }
  if (tid < 3){
    for (int k=0;k<KNB;k++){
      int idx = sKi[k];
      float pc = (tid==0 ? xs[b*N+idx] : tid==1 ? ys[b*N+idx] : zs[b*N+idx]);
      float cc = (tid==0 ? cx : tid==1 ? cy : cz);
      float w = pc - cc;
      s3 += w; s4 += w*w;
    }
  }
  float t;
  t = blockReduceSum(s1, sRed); if (tid==0) atomicAdd(&sums[0], t);
  t = blockReduceSum(s2, sRed); if (tid==0) atomicAdd(&sums[1], t);
  t = blockReduceSum(s3, sRed); if (tid==0) atomicAdd(&sums[2], t);
  t = blockReduceSum(s4, sRed); if (tid==0) atomicAdd(&sums[3], t);
}

// ---------------- main feature kernel (+ optional LDS-free FPS chunk in block 0) ----------------
template<int C, int NF, int NT>
__global__ void k_feat(const float* __restrict__ x,
            const float* __restrict__ xs, const float* __restrict__ ys, const float* __restrict__ zs,
            const float* __restrict__ nxs, const float* __restrict__ nys, const float* __restrict__ nzs,
            const int* __restrict__ fi, const int* __restrict__ ki, const float* __restrict__ sums,
            double n1, double n2,
            int N, int G, float* __restrict__ lc,
            int t0, int t1, float* __restrict__ dmnG, float4* __restrict__ cenG,
            int* __restrict__ fi2, float* __restrict__ n2xs,
            float* __restrict__ n2ys, float* __restrict__ n2zs){
  constexpr int D = 2*C;
  constexpr int D3 = D/3;
  constexpr int FD = C/3;
  __shared__ u64 candF[2][4];
  __shared__ float sLcx[C];
  __shared__ float sDx[KNB*3];
  __shared__ int sKi[KNB];
  __shared__ int sFi;
  __shared__ float sC[3];
  __shared__ float sInv2[2];
  int tid = threadIdx.x;
  if constexpr (NF > 0){
    if (blockIdx.x == 0){
      fps_chunk<NF,NT,false>(nxs, nys, nzs, t0, t1, dmnG, cenG, fi2, n2xs, n2ys, n2zs, candF, nullptr);
      return;
    }
  }
  int bid = (NF > 0) ? ((int)blockIdx.x - 1) : (int)blockIdx.x;
  int g = bid % G, b = bid / G;
  if (tid==0){ int f0 = fi[g]; if ((u32)f0 >= (u32)N) f0 = 0; sFi = f0; }
  if (tid==0){
    double s1 = sums[0], s2 = sums[1];
    double mean = s1/n1;
    double var = (s2 - s1*mean)/(n1 - 1.0); if (var < 0) var = 0;
    sInv2[0] = (float)(1.0/(sqrt(var) + 1e-5));
    double t1d = sums[2], t2d = sums[3];
    double m2 = t1d/n2;
    double v2 = (t2d - t1d*m2)/(n2 - 1.0); if (v2 < 0) v2 = 0;
    sInv2[1] = (float)(1.0/(sqrt(v2) + 1e-5));
  }
  if (tid<3) sC[tid] = (tid==0 ? nxs[b*G+g] : tid==1 ? nys[b*G+g] : nzs[b*G+g]);
  if (tid < KNB){ int v = ki[(size_t)(b*G+g)*KNB + tid]; if ((u32)v >= (u32)N) v = 0; sKi[tid] = v; }
  __syncthreads();
  for (int c = tid; c < C; c += blockDim.x) sLcx[c] = x[(size_t)(b*N + sFi)*C + c];
  for (int t = tid; t < KNB*3; t += blockDim.x){
    int k = t/3, c = t%3;
    int idx = sKi[k];
    float pc = (c==0 ? xs[b*N+idx] : c==1 ? ys[b*N+idx] : zs[b*N+idx]);
    sDx[t] = (pc - sC[c]) * sInv2[1];
  }
  __syncthreads();
  int p = tid;
  if (p >= C) return;
  int d0 = 2*p;
  int c = d0 / D3;
  int f = (d0 - c*D3) >> 1;
  float rcp = __powf(1000.0f, -(float)f / (float)FD);
  bool low = (d0 < C);
  float invdx = sInv2[0];
  float fh0 = 0.f, fh1 = 0.f;
  if (!low){ fh0 = sLcx[d0-C]; fh1 = sLcx[d0+1-C]; }
  float l0 = low ? sLcx[d0] : 0.f, l1 = low ? sLcx[d0+1] : 0.f;
  float mx0=-INFINITY, mx1=-INFINITY, sm0=0.f, sm1=0.f;
  for (int k=0;k<KNB;k++){
    float a = (100.0f * sDx[k*3+c]) * rcp;
    float sn, cs; __sincosf(a, &sn, &cs);
    float f0, f1;
    if (low){
      float2 v = *(const float2*)(x + (size_t)(b*N + sKi[k])*C + d0);
      f0 = (v.x - l0) * invdx;
      f1 = (v.y - l1) * invdx;
    } else { f0 = fh0; f1 = fh1; }
    float w0 = (f0 + sn)*sn;
    float w1 = (f1 + cs)*cs;
    mx0 = fmaxf(mx0, w0); sm0 += w0;
    mx1 = fmaxf(mx1, w1); sm1 += w1;
  }
  float* o = lc + (size_t)(b*G+g)*D + d0;
  o[0] = mx0 + sm0/90.0f;
  o[1] = mx1 + sm1/90.0f;
}

// ---------------- BatchNorm: parallel partial stats ----------------
__global__ __launch_bounds__(256)
void k_bnpart(const float* __restrict__ lc, int D, int M,
              double* __restrict__ PS, double* __restrict__ PQ){
  __shared__ double sS[4][64], sQ[4][64];
  int lane = threadIdx.x & 63, row = threadIdx.x >> 6;
  int tile = blockIdx.x, stripe = blockIdx.y;
  int d = tile*64 + lane;
  int span = M / NSTRIPE;
  int i0 = stripe * span;
  double s=0, q=0;
  if (d < D){
    for (int i=i0+row; i<i0+span; i+=4){
      float v = lc[(size_t)i*D + d];
      s += v; q += (double)v*v;
    }
  }
  sS[row][lane]=s; sQ[row][lane]=q;
  __syncthreads();
  if (row==0 && d < D){
    PS[(size_t)stripe*MAXD + d] = sS[0][lane]+sS[1][lane]+sS[2][lane]+sS[3][lane];
    PQ[(size_t)stripe*MAXD + d] = sQ[0][lane]+sQ[1][lane]+sQ[2][lane]+sQ[3][lane];
  }
}

__global__ void k_bnfin(const double* __restrict__ PS, const double* __restrict__ PQ,
                        const float* __restrict__ gamma, const float* __restrict__ beta,
                        int D, int M, float* __restrict__ A, float* __restrict__ Bb){
  int d = blockIdx.x*64 + threadIdx.x;
  if (d >= D) return;
  double ts=0, tq=0;
  for (int s=0; s<NSTRIPE; s++){ ts += PS[(size_t)s*MAXD + d]; tq += PQ[(size_t)s*MAXD + d]; }
  double mean = ts / M;
  double var = tq / M - mean*mean; if (var < 0) var = 0;
  float rstd = (float)(1.0/sqrt(var + 1e-5));
  float gm = gamma[d], bt = beta[d];
  A[d] = gm*rstd;
  Bb[d] = bt - (float)mean*gm*rstd;
}

// in-place BN + GELU — large coalesced grid
__global__ void k_apply(float* __restrict__ lc, const float* __restrict__ A,
                        const float* __restrict__ Bb, int D, int total){
  int i = blockIdx.x*blockDim.x + threadIdx.x;
  if (i >= total) return;
  int d = i % D;
  float v = lc[i]*A[d] + Bb[d];
  lc[i] = 0.5f * v * (1.0f + erff(v * 0.70710678118654752f));
}

__global__ void k_out(const float* __restrict__ feat, float* __restrict__ out){
  int i = blockIdx.x*blockDim.x + threadIdx.x;
  if (i >= BB*1152) return;
  int b = i / 1152, d = i % 1152;
  const float* base = feat + (size_t)b*256*1152 + d;
  float mx = -INFINITY, sm = 0.f;
  for (int g=0; g<256; g++){
    float v = base[(size_t)g*1152];
    mx = fmaxf(mx, v); sm += v;
  }
  out[i] = mx + sm/256.0f;
}

// ---------------- launch ----------------
extern "C" void kernel_launch(void* const* d_in, const int* in_sizes, int n_in,
                              void* d_out, int out_size, void* d_ws, size_t ws_size,
                              hipStream_t stream) {
  const float* xyz = (const float*)d_in[0];
  const float* xin = (const float*)d_in[1];
  float* ws = (float*)d_ws;
  size_t off = 0;
  const size_t PS_ = (size_t)BB*NP0;
  const size_t XS = (size_t)BB*NP0*CC0;
  float* T0[3]; float* T1[3]; float* T2[3];
  for (int i=0;i<3;i++){ T0[i] = ws + off; off += PS_; }
  for (int i=0;i<3;i++){ T1[i] = ws + off; off += PS_; }
  for (int i=0;i<3;i++){ T2[i] = ws + off; off += PS_; }
  float* xA = ws + off; off += XS;
  float* xB = ws + off; off += XS;
  int*   fiA = (int*)(ws + off); off += 2048;
  int*   fiB = (int*)(ws + off); off += 2048;
  int*   ki = (int*)(ws + off); off += (size_t)BB*2048*KNB;
  float* sums = ws + off; off += 16;
  float* Abn  = ws + off; off += 1152;
  float* Bbn  = ws + off; off += 1152;
  float* dmnG = ws + off; off += 2048;
  float4* cenG = (float4*)(ws + off); off += 4;
  off = (off + 1) & ~(size_t)1;
  double* PSb = (double*)(ws + off); off += (size_t)NSTRIPE*MAXD*2;
  double* PQb = (double*)(ws + off); off += (size_t)NSTRIPE*MAXD*2;

  k_init<<<(BB*NP0*36+255)/256, 256, 0, stream>>>(xyz, xin, T0[0], T0[1], T0[2], xA, sums);
  k_fps4<16><<<1, 256, 0, stream>>>(T0[0],T0[1],T0[2], NP0, NP0/2, fiA, T1[0],T1[1],T1[2]);

  float **P = T0, **Cn = T1, **Nx = T2;
  int *fiC = fiA, *fiN = fiB;
  float *xc = xA, *lc = xB;
  for (int s=0; s<4; s++){
    int N = NP0 >> s, G = N >> 1, C = CC0 << s, D = 2*C;
    float* ssum = sums + 4*s;
    size_t knn_need = (size_t)(N + 256 + 512 + 8 + 8)*4;
    if (s==0){
      size_t lds = knn_need; size_t fps_need = (size_t)2048*16;
      if (fps_need > lds) lds = fps_need;
      // FPS(1) chunk A: iters [1, FSPLIT), LDS staging
      k_knnstd<72,2048><<<BB*G+1, 256, lds, stream>>>(xc, P[0],P[1],P[2], Cn[0],Cn[1],Cn[2],
          fiC, N, G, ki, ssum, 1, FSPLIT, dmnG, cenG, fiN, Nx[0],Nx[1],Nx[2]);
    } else if (s==1){
      size_t lds = knn_need; size_t fps_need = (size_t)1024*16;
      if (fps_need > lds) lds = fps_need;
      k_knnstd<144,1024><<<BB*G+1, 256, lds, stream>>>(xc, P[0],P[1],P[2], Cn[0],Cn[1],Cn[2],
          fiC, N, G, ki, ssum, 1, 512, dmnG, cenG, fiN, Nx[0],Nx[1],Nx[2]);
    } else if (s==2){
      size_t lds = knn_need; size_t fps_need = (size_t)512*16;
      if (fps_need > lds) lds = fps_need;
      k_knnstd<288,512><<<BB*G+1, 256, lds, stream>>>(xc, P[0],P[1],P[2], Cn[0],Cn[1],Cn[2],
          fiC, N, G, ki, ssum, 1, 256, dmnG, cenG, fiN, Nx[0],Nx[1],Nx[2]);
    } else {
      k_knnstd<576,0><<<BB*G, 256, knn_need, stream>>>(xc, P[0],P[1],P[2], Cn[0],Cn[1],Cn[2],
          fiC, N, G, ki, ssum, 0, 0, nullptr, nullptr, nullptr, nullptr, nullptr, nullptr);
    }
    double n1 = (double)BB*G*KNB*C, n2 = (double)BB*G*KNB*3;
    int Tp = ((C + 63)/64)*64;
    if (s==0){
      // FPS(1) chunk B: iters [FSPLIT, 1024) + gather; LDS-free (global winner reads)
      k_feat<72,2048,128><<<BB*G+1, Tp, 0, stream>>>(xc, P[0],P[1],P[2], Cn[0],Cn[1],Cn[2], fiC, ki, ssum,
          n1, n2, N, G, lc, FSPLIT, 1024, dmnG, cenG, fiN, Nx[0],Nx[1],Nx[2]);
    } else if (s==1){
      k_feat<144,0,0><<<BB*G, Tp, 0, stream>>>(xc, P[0],P[1],P[2], Cn[0],Cn[1],Cn[2], fiC, ki, ssum,
          n1, n2, N, G, lc, 0, 0, nullptr, nullptr, nullptr, nullptr, nullptr, nullptr);
    } else if (s==2){
      k_feat<288,0,0><<<BB*G, Tp, 0, stream>>>(xc, P[0],P[1],P[2], Cn[0],Cn[1],Cn[2], fiC, ki, ssum,
          n1, n2, N, G, lc, 0, 0, nullptr, nullptr, nullptr, nullptr, nullptr, nullptr);
    } else {
      k_feat<576,0,0><<<BB*G, Tp, 0, stream>>>(xc, P[0],P[1],P[2], Cn[0],Cn[1],Cn[2], fiC, ki, ssum,
          n1, n2, N, G, lc, 0, 0, nullptr, nullptr, nullptr, nullptr, nullptr, nullptr);
    }
    int M = BB*G;
    dim3 bng((D + 63)/64, NSTRIPE);
    k_bnpart<<<bng, 256, 0, stream>>>(lc, D, M, PSb, PQb);
    k_bnfin<<<(D + 63)/64, 64, 0, stream>>>(PSb, PQb, (const float*)d_in[2+2*s],
                                            (const float*)d_in[3+2*s], D, M, Abn, Bbn);
    int total = M*D;
    k_apply<<<(total+255)/256, 256, 0, stream>>>(lc, Abn, Bbn, D, total);
    float** t = P; P = Cn; Cn = Nx; Nx = t;
    int* ti = fiC; fiC = fiN; fiN = ti;
    float* tf = xc; xc = lc; lc = tf;
  }
  k_out<<<(BB*1152+255)/256, 256, 0, stream>>>(xc, (float*)d_out);
}